// Round 15
// baseline (69.415 us; speedup 1.0000x reference)
//
#include <hip/hip_runtime.h>
#include <hip/hip_bf16.h>

// MultiHeadAttention fused forward, MI355X/gfx950.
// B=2, S=2048, D_IN=768, H=12, D=64.  out[b,s,h*64+e] fp32.
//
// Pipeline:
//   1. prep    : x -> bf16 pre-swizzled A-images; W -> pre-swizzled B-images.
//   2. proj_qkv: DMA-staged dbuf MFMA GEMM (r6-proven sync).  Q prescaled,
//                K/Vt pre-swizzled images.
//   3. attn    : SPLIT-K flash attention with XCD-LOCAL dispatch (r15):
//                bid%8 = XCD (round-robin heuristic); XCD x owns bh in
//                {x, x+8, x+16} -> 3MB K/V working set fits the 4MB per-XCD
//                L2, so the per-iter DMA drain waits on L2 (~200cy) not HBM
//                (~900cy).  144 blocks/XCD, sizes descending (LPT), per-XCD
//                iter sums identical.  Per-iter body identical to r13/r14.
//   4. combine : merge split partials -> out.
//
// Workspace: wtb [0,3538944) | Q [3538944,9830400) | Ksw [9830400,16121856)
//            Vtsw [16121856,22413312) | xb [22413312,28704768)
//            Obuf [28704768,41287680) | mlbuf [41287680,41680896)

typedef short bf16x8 __attribute__((ext_vector_type(8)));
typedef short bf16x4 __attribute__((ext_vector_type(4)));
typedef float f32x4  __attribute__((ext_vector_type(4)));

#define MFMA16(a, b, c)  __builtin_amdgcn_mfma_f32_16x16x32_bf16((a), (b), (c), 0, 0, 0)
#define MFMAK16(a, b, c) __builtin_amdgcn_mfma_f32_16x16x16bf16_1k((a), (b), (c), 0, 0, 0)

static __device__ __forceinline__ unsigned short f2bf(float f) {
    unsigned int u = __builtin_bit_cast(unsigned int, f);
    u += 0x7fffu + ((u >> 16) & 1u);
    return (unsigned short)(u >> 16);
}

// XOR swizzle for [row][128B] tiles (conflict-free b128 column slices).
static __device__ __forceinline__ int sw(int row, int cb) {
    return (row << 7) + (cb ^ ((row & 7) << 4));
}

// async 16B global->LDS DMA (HW: wave-uniform LDS base + lane*16)
static __device__ __forceinline__ void gld16(const void* g, void* l) {
    __builtin_amdgcn_global_load_lds(
        (__attribute__((address_space(1))) void*)g,
        (__attribute__((address_space(3))) void*)l, 16, 0, 0);
}

// ---------------------------------------------------------------------------
// Kernel 1 (merged preps).  grid 1200.
// ---------------------------------------------------------------------------
__global__ __launch_bounds__(256) void prep(const float* __restrict__ x,
                                            const float* __restrict__ Wq,
                                            const float* __restrict__ Wk,
                                            const float* __restrict__ Wv,
                                            char* __restrict__ xb,
                                            char* __restrict__ wtb) {
    __shared__ float tile[64][65];
    const int bid = blockIdx.x;
    const int t = threadIdx.x;
    if (bid < 768) {
        const int stile = bid & 63, ks = bid >> 6;
        const int row = t >> 2, k16 = (t & 3) * 16;
        const float* src = x + (size_t)(stile * 64 + row) * 768 + ks * 64 + k16;
        char* img = xb + ((size_t)stile * 12 + ks) * 8192;
        const float4 v0 = *(const float4*)(src);
        const float4 v1 = *(const float4*)(src + 4);
        const float4 v2 = *(const float4*)(src + 8);
        const float4 v3 = *(const float4*)(src + 12);
        bf16x8 o0, o1;
        o0[0] = (short)f2bf(v0.x); o0[1] = (short)f2bf(v0.y);
        o0[2] = (short)f2bf(v0.z); o0[3] = (short)f2bf(v0.w);
        o0[4] = (short)f2bf(v1.x); o0[5] = (short)f2bf(v1.y);
        o0[6] = (short)f2bf(v1.z); o0[7] = (short)f2bf(v1.w);
        o1[0] = (short)f2bf(v2.x); o1[1] = (short)f2bf(v2.y);
        o1[2] = (short)f2bf(v2.z); o1[3] = (short)f2bf(v2.w);
        o1[4] = (short)f2bf(v3.x); o1[5] = (short)f2bf(v3.y);
        o1[6] = (short)f2bf(v3.z); o1[7] = (short)f2bf(v3.w);
        *(bf16x8*)(img + sw(row, k16 * 2)) = o0;
        *(bf16x8*)(img + sw(row, k16 * 2 + 16)) = o1;
    } else {
        const int idx = bid - 768;
        const int wh = idx % 36, dt = idx / 36;
        const int w = wh / 12, h = wh % 12;
        const float* W = (w == 0) ? Wq : (w == 1) ? Wk : Wv;
        for (int i = 0; i < 4; ++i) {
            int c = t + i * 256;
            int d = c >> 4, e4 = (c & 15) * 4;
            const float4 v = *(const float4*)(W + (size_t)(h * 768 + dt * 64 + d) * 64 + e4);
            tile[d][e4 + 0] = v.x; tile[d][e4 + 1] = v.y;
            tile[d][e4 + 2] = v.z; tile[d][e4 + 3] = v.w;
        }
        __syncthreads();
        char* img = wtb + ((size_t)(wh * 12) + dt) * 8192;
        for (int i = 0; i < 4; ++i) {
            int c = t + i * 256;
            int e = c >> 4, d4 = (c & 15) * 4;
            ushort4 o;
            o.x = f2bf(tile[d4 + 0][e]); o.y = f2bf(tile[d4 + 1][e]);
            o.z = f2bf(tile[d4 + 2][e]); o.w = f2bf(tile[d4 + 3][e]);
            *(ushort4*)(img + e * 128 + ((d4 * 2) ^ ((e & 7) << 4))) = o;
        }
    }
}

// ---------------------------------------------------------------------------
// Kernel 2: QKV projection.  grid (64 stile, 12 h), 4 waves, DMA dbuf.
// ---------------------------------------------------------------------------
__global__ __launch_bounds__(256) void proj_qkv(const char* __restrict__ xb,
                                                const char* __restrict__ wtb,
                                                unsigned short* __restrict__ q,
                                                unsigned short* __restrict__ ksw,
                                                char* __restrict__ vsw) {
    __shared__ __align__(16) char smem[65536];   // [2 buf][4 img][8192]
    const int stile = blockIdx.x;
    const int h = blockIdx.y;
    const int t = threadIdx.x;
    const int wave = t >> 6, lane = t & 63;
    const int lhi = lane >> 4, llo = lane & 15;
    const int wr = wave >> 1, wc = wave & 1;

    const char* asrc = xb + (size_t)stile * 12 * 8192;

    f32x4 acc[3][2][2] = {};

    #define STAGE(KS, BUF)                                                       \
        do {                                                                     \
            const char* s0 = asrc + (KS) * 8192;                                 \
            char* d0 = smem + (BUF) * 32768;                                     \
            gld16(s0 + t * 16, d0 + t * 16);                                     \
            gld16(s0 + t * 16 + 4096, d0 + t * 16 + 4096);                       \
            for (int w3 = 0; w3 < 3; ++w3) {                                     \
                const char* s1 = wtb + ((size_t)((w3 * 12 + h) * 12) + (KS)) * 8192; \
                char* d1 = smem + (BUF) * 32768 + (1 + w3) * 8192;               \
                gld16(s1 + t * 16, d1 + t * 16);                                 \
                gld16(s1 + t * 16 + 4096, d1 + t * 16 + 4096);                   \
            }                                                                    \
        } while (0)

    STAGE(0, 0);
    __syncthreads();
    int cur = 0;
    for (int ks = 0; ks < 12; ++ks) {
        if (ks < 11) STAGE(ks + 1, cur ^ 1);   // prefetch overlaps compute below
        char* Alds = smem + cur * 32768;
        #pragma unroll
        for (int kk = 0; kk < 2; ++kk) {
            bf16x8 a[2];
            #pragma unroll
            for (int m = 0; m < 2; ++m)
                a[m] = *(const bf16x8*)(Alds + sw(wr * 32 + m * 16 + llo, kk * 64 + lhi * 16));
            #pragma unroll
            for (int w3 = 0; w3 < 3; ++w3) {
                char* Blds = Alds + (1 + w3) * 8192;
                #pragma unroll
                for (int n = 0; n < 2; ++n) {
                    bf16x8 b = *(const bf16x8*)(Blds + sw(wc * 32 + n * 16 + llo, kk * 64 + lhi * 16));
                    #pragma unroll
                    for (int m = 0; m < 2; ++m)
                        acc[w3][m][n] = MFMA16(a[m], b, acc[w3][m][n]);
                }
            }
        }
        __syncthreads();   // drains DMA + orders buffer reuse
        cur ^= 1;
    }
    #undef STAGE

    const float SCALE_Q = 0.18033688011112042f;  // 0.125 * log2(e)
    const int bglob = stile >> 5, ktile = stile & 31;
    const int bh = bglob * 12 + h;
    #pragma unroll
    for (int m = 0; m < 2; ++m)
        for (int n = 0; n < 2; ++n)
            for (int r = 0; r < 4; ++r) {
                int s = (stile * 64 + wr * 32 + m * 16 + lhi * 4 + r) & 2047;
                int e = wc * 32 + n * 16 + llo;
                q[(size_t)(bh * 2048 + s) * 64 + e] = f2bf(acc[0][m][n][r] * SCALE_Q);
            }
    unsigned short* kdst = ksw + ((size_t)bh * 32 + ktile) * 4096;
    #pragma unroll
    for (int m = 0; m < 2; ++m)
        for (int n = 0; n < 2; ++n)
            for (int r = 0; r < 4; ++r) {
                int kk = wr * 32 + m * 16 + lhi * 4 + r;
                int e = wc * 32 + n * 16 + llo;
                kdst[kk * 64 + (e ^ ((kk & 7) << 3))] = f2bf(acc[1][m][n][r]);
            }
    char* vtimg = smem;
    __syncthreads();
    #pragma unroll
    for (int m = 0; m < 2; ++m)
        for (int n = 0; n < 2; ++n)
            for (int r = 0; r < 4; ++r) {
                int kk = wr * 32 + m * 16 + lhi * 4 + r;
                int e = wc * 32 + n * 16 + llo;
                int pos = (((kk >> 2) & 3) * 32 + (kk >> 4) * 8 + (kk & 3) * 2) ^ ((e & 7) << 4);
                *(unsigned short*)(vtimg + e * 128 + pos) = f2bf(acc[2][m][n][r]);
            }
    __syncthreads();
    {
        char* dst = vsw + ((size_t)bh * 32 + ktile) * 8192;
        #pragma unroll
        for (int i = 0; i < 2; ++i)
            *(float4*)(dst + t * 16 + i * 4096) =
                *(const float4*)(vtimg + t * 16 + i * 4096);
    }
}

// ---------------------------------------------------------------------------
// Kernel 3: split-K flash attention, XCD-local dispatch.  grid 1152 x 256 thr.
// bid%8 = XCD (round-robin heuristic); XCD x owns bh in {x, x+8, x+16}.
// slot = bid/8 (0..143): bh = x + 8*(slot%3); j = slot/3 (0..47) indexes the
// per-bh piece table, sizes descending (LPT within XCD):
//   j<16 : part0 of qt=16+j (kt 0..15, no diag)      size 16
//   j=16 : single qt=15                              size 16
//   j=17 : part1 of qt=31 (kt 16..31, diag)          size 16
//   j>=18: g=(j-18)/2, s=15-g:
//          even -> single qt=s-1                     size s
//          odd  -> part1 of qt=s+15 (kt 16..qt)      size s
// Split blocks write unnormalized fp32 (O,m,l); singles write out directly.
// Per-iter body identical to r13/r14 (proven).
// ---------------------------------------------------------------------------
__global__ __launch_bounds__(256) void attn(const unsigned short* __restrict__ Q,
                                            const char* __restrict__ Ksw,
                                            const char* __restrict__ Vsw,
                                            float* __restrict__ out,
                                            float* __restrict__ Obuf,
                                            float* __restrict__ mlbuf) {
    __shared__ __align__(16) char smem[32768];  // K dbuf [0,16K) | Vt dbuf [16K,32K)
    const int t = threadIdx.x, wave = t >> 6, lane = t & 63;
    const int lhi = lane >> 4, llo = lane & 15;
    const int bid = blockIdx.x;
    const int xcd = bid & 7, slot = bid >> 3;
    const int bh = xcd + 8 * (slot % 3);
    const int j = slot / 3;                   // 0..47, sizes descending
    int qt, kts, kte, part = 0;
    bool split;
    if (j < 16)       { qt = 16 + j; part = 0; kts = 0;  kte = 15; split = true;  }
    else if (j == 16) { qt = 15;               kts = 0;  kte = 15; split = false; }
    else if (j == 17) { qt = 31;     part = 1; kts = 16; kte = 31; split = true;  }
    else {
        const int g = (j - 18) >> 1;          // 0..14, size s = 15-g
        const int s = 15 - g;
        if (((j - 18) & 1) == 0) { qt = s - 1;            kts = 0;  kte = qt; split = false; }
        else                     { qt = s + 15; part = 1; kts = 16; kte = qt; split = true;  }
    }
    const unsigned short* Qg = Q + (size_t)bh * 2048 * 64;
    const char* Kg = Ksw + (size_t)bh * 32 * 8192;
    const char* Vg = Vsw + (size_t)bh * 32 * 8192;

    const int q0 = qt * 64 + wave * 16;      // lane's q-row = q0 + llo
    bf16x8 qa[2];
    #pragma unroll
    for (int kk = 0; kk < 2; ++kk)
        qa[kk] = *(const bf16x8*)(Qg + (size_t)(q0 + llo) * 64 + kk * 32 + lhi * 8);

    f32x4 acc[4] = {};                       // O^T: acc[n][r] -> e = n*16+lhi*4+r, q = llo
    float m_r = -1e30f, l_r = 0.f;

    #define ASTAGE(KT, BUF)                                              \
        do {                                                             \
            const char* ks_ = Kg + (size_t)(KT) * 8192;                  \
            const char* vs_ = Vg + (size_t)(KT) * 8192;                  \
            char* kd = smem + (BUF) * 8192;                              \
            char* vd = smem + 16384 + (BUF) * 8192;                      \
            gld16(ks_ + t * 16, kd + t * 16);                            \
            gld16(ks_ + t * 16 + 4096, kd + t * 16 + 4096);              \
            gld16(vs_ + t * 16, vd + t * 16);                            \
            gld16(vs_ + t * 16 + 4096, vd + t * 16 + 4096);              \
        } while (0)

    ASTAGE(kts, 0);
    __syncthreads();
    int cur = 0;
    for (int kt = kts; kt <= kte; ++kt) {
        if (kt < kte) ASTAGE(kt + 1, cur ^ 1);   // prefetch overlaps compute below
        char* Kb = smem + cur * 8192;
        char* Vb = smem + 16384 + cur * 8192;

        // S^T = K Q^T: sc[n][r] -> k-pos = n*16+lhi*4+r, q = llo
        f32x4 sc[4];
        __builtin_amdgcn_s_setprio(1);
        #pragma unroll
        for (int n = 0; n < 4; ++n) {
            f32x4 z = {};
            #pragma unroll
            for (int kk = 0; kk < 2; ++kk) {
                bf16x8 bk = *(const bf16x8*)(Kb + sw(n * 16 + llo, kk * 64 + lhi * 16));
                z = MFMA16(bk, qa[kk], z);
            }
            sc[n] = z;
        }
        __builtin_amdgcn_s_setprio(0);
        // V fragments -> registers (LDS pipe overlaps softmax below)
        bf16x8 vfr[4][2];
        #pragma unroll
        for (int n = 0; n < 4; ++n) {
            const int row = n * 16 + llo;
            vfr[n][0] = *(const bf16x8*)(Vb + sw(row, lhi * 32));
            vfr[n][1] = *(const bf16x8*)(Vb + sw(row, lhi * 32 + 16));
        }
        if (kt == qt) {   // causal mask, diagonal tile only (part0 never hits)
            #pragma unroll
            for (int n = 0; n < 4; ++n)
                #pragma unroll
                for (int r = 0; r < 4; ++r)
                    if (kt * 64 + n * 16 + lhi * 4 + r > q0 + llo) sc[n][r] = -1e30f;
        }
        // per-lane max over this lane's 16 scores
        float pmax = fmaxf(
            fmaxf(fmaxf(fmaxf(sc[0][0], sc[0][1]), fmaxf(sc[0][2], sc[0][3])),
                  fmaxf(fmaxf(sc[1][0], sc[1][1]), fmaxf(sc[1][2], sc[1][3]))),
            fmaxf(fmaxf(fmaxf(sc[2][0], sc[2][1]), fmaxf(sc[2][2], sc[2][3])),
                  fmaxf(fmaxf(sc[3][0], sc[3][1]), fmaxf(sc[3][2], sc[3][3]))));
        // defer-max: rescale only if some row's max grew by > 8 (exp2 units)
        if (__any(pmax > m_r + 8.0f)) {
            float tm = fmaxf(pmax, __shfl_xor(pmax, 16, 64));
            tm = fmaxf(tm, __shfl_xor(tm, 32, 64));
            float nm = fmaxf(m_r, tm);
            float corr = exp2f(m_r - nm);             // first tile: -> 0
            m_r = nm;
            l_r *= corr;
            #pragma unroll
            for (int n = 0; n < 4; ++n)
                #pragma unroll
                for (int r = 0; r < 4; ++r) acc[n][r] *= corr;
        }
        // P = exp2(sc - m_r), packed straight into mfma16x16 B-fragments
        bf16x4 pf[4];
        float ps = 0.f;
        #pragma unroll
        for (int kb = 0; kb < 4; ++kb) {
            float p0 = exp2f(sc[kb][0] - m_r), p1 = exp2f(sc[kb][1] - m_r);
            float p2 = exp2f(sc[kb][2] - m_r), p3 = exp2f(sc[kb][3] - m_r);
            ps += (p0 + p1) + (p2 + p3);
            unsigned int w0, w1;
            asm("v_cvt_pk_bf16_f32 %0, %1, %2" : "=v"(w0) : "v"(p0), "v"(p1));
            asm("v_cvt_pk_bf16_f32 %0, %1, %2" : "=v"(w1) : "v"(p2), "v"(p3));
            unsigned long long u = ((unsigned long long)w1 << 32) | w0;
            pf[kb] = __builtin_bit_cast(bf16x4, u);
        }
        l_r += ps;
        // O^T += V^T P — PV entirely from registers (vfr + pf)
        __builtin_amdgcn_s_setprio(1);
        #pragma unroll
        for (int n = 0; n < 4; ++n) {
            f32x4 a = acc[n];
            a = MFMAK16(__builtin_shufflevector(vfr[n][0], vfr[n][0], 0, 1, 2, 3), pf[0], a);
            a = MFMAK16(__builtin_shufflevector(vfr[n][0], vfr[n][0], 4, 5, 6, 7), pf[1], a);
            a = MFMAK16(__builtin_shufflevector(vfr[n][1], vfr[n][1], 0, 1, 2, 3), pf[2], a);
            a = MFMAK16(__builtin_shufflevector(vfr[n][1], vfr[n][1], 4, 5, 6, 7), pf[3], a);
            acc[n] = a;
        }
        __builtin_amdgcn_s_setprio(0);
        if (kt < kte) __syncthreads();   // drains DMA + orders buffer reuse
        cur ^= 1;
    }
    #undef ASTAGE
    // finish the deferred l reduction (4 lhi partials of row q=llo)
    l_r += __shfl_xor(l_r, 16, 64);
    l_r += __shfl_xor(l_r, 32, 64);
    if (split) {
        // unnormalized partial: O (fp32), m, l
        const int p = ((bh * 16) + (qt - 16)) * 2 + part;
        float* Ob = Obuf + (size_t)p * 4096;
        const int qrow = wave * 16 + llo;    // 0..63 within tile
        #pragma unroll
        for (int n = 0; n < 4; ++n) {
            float4 o;
            o.x = acc[n][0]; o.y = acc[n][1]; o.z = acc[n][2]; o.w = acc[n][3];
            *(float4*)(Ob + qrow * 64 + n * 16 + lhi * 4) = o;
        }
        if (lhi == 0) {
            float2 ml; ml.x = m_r; ml.y = l_r;
            *(float2*)(mlbuf + (size_t)p * 128 + qrow * 2) = ml;
        }
    } else {
        const float inv = 1.0f / l_r;
        const int b = bh / 12, h = bh - b * 12;
        #pragma unroll
        for (int n = 0; n < 4; ++n) {
            float4 o;
            o.x = acc[n][0] * inv; o.y = acc[n][1] * inv;
            o.z = acc[n][2] * inv; o.w = acc[n][3] * inv;
            *(float4*)(out + (size_t)(b * 2048 + q0 + llo) * 768 + h * 64 + n * 16 + lhi * 4) = o;
        }
    }
}

// ---------------------------------------------------------------------------
// Kernel 4: combine split partials.  grid 384 (bh x qt>=16), 256 thr.
// O = (O0*w0 + O1*w1) / (l0*w0 + l1*w1), w_i = 2^(m_i - max(m0,m1)).
// ---------------------------------------------------------------------------
__global__ __launch_bounds__(256) void combine(const float* __restrict__ Obuf,
                                               const float* __restrict__ mlbuf,
                                               float* __restrict__ out) {
    const int bid = blockIdx.x;
    const int bh = bid % 24, qt = 16 + bid / 24;
    const int b = bh / 12, h = bh - b * 12;
    const int t = threadIdx.x;
    const int r = t >> 2, c0 = (t & 3) * 16;
    const int p0 = ((bh * 16) + (qt - 16)) * 2;
    const float2 ml0 = *(const float2*)(mlbuf + (size_t)p0 * 128 + r * 2);
    const float2 ml1 = *(const float2*)(mlbuf + (size_t)(p0 + 1) * 128 + r * 2);
    const float mm = fmaxf(ml0.x, ml1.x);
    const float w0 = exp2f(ml0.x - mm), w1 = exp2f(ml1.x - mm);
    const float inv = 1.0f / (ml0.y * w0 + ml1.y * w1);
    const float* s0 = Obuf + (size_t)p0 * 4096 + r * 64 + c0;
    const float* s1 = s0 + 4096;
    float* dst = out + (size_t)(b * 2048 + qt * 64 + r) * 768 + h * 64 + c0;
    #pragma unroll
    for (int i = 0; i < 4; ++i) {
        const float4 a = *(const float4*)(s0 + i * 4);
        const float4 c = *(const float4*)(s1 + i * 4);
        float4 o;
        o.x = (a.x * w0 + c.x * w1) * inv;
        o.y = (a.y * w0 + c.y * w1) * inv;
        o.z = (a.z * w0 + c.z * w1) * inv;
        o.w = (a.w * w0 + c.w * w1) * inv;
        *(float4*)(dst + i * 4) = o;
    }
}

// ---------------------------------------------------------------------------
extern "C" void kernel_launch(void* const* d_in, const int* in_sizes, int n_in,
                              void* d_out, int out_size, void* d_ws, size_t ws_size,
                              hipStream_t stream) {
    const float* x  = (const float*)d_in[0];
    const float* Wq = (const float*)d_in[1];
    const float* Wk = (const float*)d_in[2];
    const float* Wv = (const float*)d_in[3];
    float* out = (float*)d_out;

    char* ws = (char*)d_ws;
    char*           wtb   = ws;                                 // 3.54 MB
    unsigned short* q     = (unsigned short*)(ws + 3538944);    // 6.29 MB
    unsigned short* ksw   = (unsigned short*)(ws + 9830400);    // 6.29 MB
    char*           vsw   = (char*)(ws + 16121856);             // 6.29 MB
    char*           xb    = (char*)(ws + 22413312);             // 6.29 MB
    float*          Obuf  = (float*)(ws + 28704768);            // 12.58 MB
    float*          mlbuf = (float*)(ws + 41287680);            // 0.39 MB
    // requires ws_size >= 41680896 bytes

    hipLaunchKernelGGL(prep, dim3(1200), dim3(256), 0, stream, x, Wq, Wk, Wv, xb, wtb);
    hipLaunchKernelGGL(proj_qkv, dim3(64, 12), dim3(256), 0, stream,
                       xb, wtb, q, ksw, vsw);
    hipLaunchKernelGGL(attn, dim3(1152), dim3(256), 0, stream,
                       q, (const char*)ksw, vsw, out, Obuf, mlbuf);
    hipLaunchKernelGGL(combine, dim3(384), dim3(256), 0, stream, Obuf, mlbuf, out);
}